// Round 2
// baseline (170.133 us; speedup 1.0000x reference)
//
#include <hip/hip_runtime.h>

typedef unsigned int uint;
typedef unsigned short ushort;

using bf16x8 = __attribute__((ext_vector_type(8))) short;
using f32x4  = __attribute__((ext_vector_type(4))) float;

// ---- bf16 helpers (bf16 = upper 16 bits of fp32) ----
__device__ __forceinline__ float b2f(ushort u) {
  union { uint i; float f; } v; v.i = ((uint)u) << 16; return v.f;
}
// round-to-nearest-even fp32 -> bf16
__device__ __forceinline__ ushort f2b(float f) {
  union { float f; uint i; } v; v.f = f;
  uint r = (v.i + 0x7fffu + ((v.i >> 16) & 1u)) >> 16;
  return (ushort)r;
}
__device__ __forceinline__ bf16x8 ldfrag(const ushort* p) {
  union { uint4 u; bf16x8 v; } x; x.u = *(const uint4*)p; return x.v;
}

// =====================================================================
// Kernel 1: per-thread conv pipeline, x fully register-resident.
// x[128] f32 -> 12x12 grid -> conv3x3(1->3)+pool+relu
// -> conv3x3(3->6)+pool+relu -> h2[54] -> ws row of 64 bf16 (pad 0)
//
// R1/R2: baseline build allocated only 84 VGPRs -> compiler remat'd
// xv[*] as repeated global loads per conv1 tap; at 2 waves/SIMD (grid-
// capped: 131072 threads over 1024 SIMDs) those latencies can't hide
// -> VALUBusy 25%. Pin xv into VGPRs via opaque asm identity (cannot
// be rematerialized from memory). launch_bounds(256,1): 512-VGPR
// budget — occupancy is grid-capped at 2 waves/SIMD anyway, so the
// loose bound costs nothing and removes spill risk.
// =====================================================================
__global__ __launch_bounds__(256, 1) void conv_kernel(
    const float* __restrict__ x,
    const float* __restrict__ w1g, const float* __restrict__ b1g,
    const float* __restrict__ w2g, const float* __restrict__ b2g,
    ushort* __restrict__ h2ws) {
  const int s = blockIdx.x * 256 + threadIdx.x;
  const float* xs = x + (size_t)s * 128;

  // whole sample in registers: grid(r,c) = xv[12r+c] for 12r+c<128 else 0
  float xv[128];
#pragma unroll
  for (int i = 0; i < 32; ++i) {
    const float4 v = ((const float4*)xs)[i];
    xv[4 * i + 0] = v.x; xv[4 * i + 1] = v.y;
    xv[4 * i + 2] = v.z; xv[4 * i + 3] = v.w;
  }
  // Pin: force each xv element to be a VGPR-resident opaque value.
  // (asm output cannot be rematerialized by reloading from global.)
#pragma unroll
  for (int i = 0; i < 128; ++i) asm("" : "+v"(xv[i]));

  float w1[3][9], b1[3];
#pragma unroll
  for (int c = 0; c < 3; ++c) {
    b1[c] = b1g[c];
#pragma unroll
    for (int q = 0; q < 9; ++q) w1[c][q] = w1g[c * 9 + q];
  }

  float h1[3][6][6];
#pragma unroll
  for (int pr = 0; pr < 6; ++pr)
#pragma unroll
    for (int pc = 0; pc < 6; ++pc)
#pragma unroll
      for (int ch = 0; ch < 3; ++ch) {
        float m = -3.0e38f;
#pragma unroll
        for (int dr = 0; dr < 2; ++dr)
#pragma unroll
          for (int dc = 0; dc < 2; ++dc) {
            float a = 0.f;
#pragma unroll
            for (int ky = 0; ky < 3; ++ky)
#pragma unroll
              for (int kx = 0; kx < 3; ++kx) {
                const int r = 2 * pr + dr + ky - 1;
                const int c = 2 * pc + dc + kx - 1;
                if (r >= 0 && r < 12 && c >= 0 && c < 12 && (12 * r + c) < 128)
                  a = fmaf(w1[ch][ky * 3 + kx], xv[12 * r + c], a);  // folds
              }
            m = fmaxf(m, a);
          }
        h1[ch][pr][pc] = fmaxf(m + b1[ch], 0.f);
      }

  // conv2 (3->6) + pool + relu -> h2[54] (NCHW flatten: o*9 + qr*3 + qc)
  float h2[54];
#pragma unroll
  for (int o = 0; o < 6; ++o) {
    float w2[27];
#pragma unroll
    for (int q = 0; q < 27; ++q) w2[q] = w2g[o * 27 + q];
    const float bo = b2g[o];
#pragma unroll
    for (int qr = 0; qr < 3; ++qr)
#pragma unroll
      for (int qc = 0; qc < 3; ++qc) {
        float m = -3.0e38f;
#pragma unroll
        for (int dr = 0; dr < 2; ++dr)
#pragma unroll
          for (int dc = 0; dc < 2; ++dc) {
            float a = 0.f;
#pragma unroll
            for (int i = 0; i < 3; ++i)
#pragma unroll
              for (int ky = 0; ky < 3; ++ky)
#pragma unroll
                for (int kx = 0; kx < 3; ++kx) {
                  const int yy = 2 * qr + dr + ky - 1;
                  const int xx = 2 * qc + dc + kx - 1;
                  if (yy >= 0 && yy < 6 && xx >= 0 && xx < 6)  // folds
                    a = fmaf(w2[i * 9 + ky * 3 + kx], h1[i][yy][xx], a);
                }
            m = fmaxf(m, a);
          }
        h2[o * 9 + qr * 3 + qc] = fmaxf(m + bo, 0.f);
      }
  }

  // pack to bf16, pad k=54..63 with zeros (MFMA K=64 relies on this)
  uint pk[32];
#pragma unroll
  for (int q = 0; q < 27; ++q)
    pk[q] = (uint)f2b(h2[2 * q]) | ((uint)f2b(h2[2 * q + 1]) << 16);
#pragma unroll
  for (int q = 27; q < 32; ++q) pk[q] = 0u;
  uint4* dst = (uint4*)(h2ws + (size_t)s * 64);
#pragma unroll
  for (int i = 0; i < 8; ++i) {
    uint4 v; v.x = pk[4 * i]; v.y = pk[4 * i + 1];
    v.z = pk[4 * i + 2]; v.w = pk[4 * i + 3];
    dst[i] = v;
  }
}

// =====================================================================
// Kernel 2: fused FC via bf16 MFMA 16x16x32.
// 256 threads = 4 waves; 128 samples/block; wave w owns samples 32w..32w+31.
// phase1: t = relu(h2 @ fc1_w^T + b)  M=128 N=128 K=64 (zero-padded)
// phase2: out = t @ out_w^T + out_b   M=128 N=128 K=128
// LDS union: {h2s+w1s 36.9KB} / {tA+owB 69.6KB} + biases -> 70.7 KB,
// 2 blocks/CU. All tiles 16B-aligned rows; strides 72/136 (2-way only).
// =====================================================================
__global__ __launch_bounds__(256, 2) void fc_kernel(
    const ushort* __restrict__ h2ws,
    const float* __restrict__ fc1w, const float* __restrict__ fc1b,
    const float* __restrict__ outw, const float* __restrict__ outb,
    float* __restrict__ out) {
  __shared__ __align__(16) union {
    struct { ushort h2s[128][72]; ushort w1s[128][72]; } p1;   // 36864 B
    struct { ushort tA[128][136]; ushort owB[128][136]; } p2;  // 69632 B
  } U;
  __shared__ float fb1[128], ob[128];

  const int t = threadIdx.x;
  const int s0 = blockIdx.x * 128;
  const int lane = t & 63, wv = t >> 6;
  const int quad = lane >> 4, lm = lane & 15;

  if (t < 128) { fb1[t] = fc1b[t]; ob[t] = outb[t]; }

  // stage h2s: 128 samples x 64 bf16 (k 54..63 already zero in ws)
#pragma unroll
  for (int i = 0; i < 4; ++i) {
    const int f = t + 256 * i;            // 0..1023 uint4s
    const int si = f >> 3, kb = f & 7;
    *(uint4*)&U.p1.h2s[si][kb * 8] =
        *(const uint4*)(h2ws + (size_t)(s0 + si) * 64 + kb * 8);
  }
  // stage fc1_w [128][54] fp32 -> bf16 B-layout [n][k]
#pragma unroll
  for (int i = 0; i < 27; ++i) {
    const int f = t + 256 * i;            // 0..6911
    const int n = f / 54, k = f - 54 * n;
    U.p1.w1s[n][k] = f2b(fc1w[f]);
  }
  // zero-pad w1s k=54..63 (byte offset 108, dword aligned)
  if (t < 128) {
    uint* p = (uint*)&U.p1.w1s[t][54];
#pragma unroll
    for (int q = 0; q < 5; ++q) p[q] = 0u;
  }
  __syncthreads();

  // ---- phase1 MFMA: acc[mt][nt] = h2[32wv+16mt ..][k] * w1[16nt ..][k]
  f32x4 acc[2][8];
#pragma unroll
  for (int mt = 0; mt < 2; ++mt)
#pragma unroll
    for (int nt = 0; nt < 8; ++nt) acc[mt][nt] = (f32x4){0.f, 0.f, 0.f, 0.f};

#pragma unroll
  for (int kk = 0; kk < 2; ++kk) {
    const int ko = kk * 32 + quad * 8;
    bf16x8 a[2], b[8];
#pragma unroll
    for (int mt = 0; mt < 2; ++mt)
      a[mt] = ldfrag(&U.p1.h2s[32 * wv + 16 * mt + lm][ko]);
#pragma unroll
    for (int nt = 0; nt < 8; ++nt)
      b[nt] = ldfrag(&U.p1.w1s[16 * nt + lm][ko]);
#pragma unroll
    for (int mt = 0; mt < 2; ++mt)
#pragma unroll
      for (int nt = 0; nt < 8; ++nt)
        acc[mt][nt] = __builtin_amdgcn_mfma_f32_16x16x32_bf16(
            a[mt], b[nt], acc[mt][nt], 0, 0, 0);
  }
  __syncthreads();  // phase1 LDS reads complete before union overwrite

  // t = relu(acc + b) -> bf16 -> tA (A-layout rows=samples, cols=j)
#pragma unroll
  for (int mt = 0; mt < 2; ++mt)
#pragma unroll
    for (int nt = 0; nt < 8; ++nt) {
      const int col = 16 * nt + lm;
      const float bj = fb1[col];
#pragma unroll
      for (int r = 0; r < 4; ++r) {
        const int row = 32 * wv + 16 * mt + quad * 4 + r;
        U.p2.tA[row][col] = f2b(fmaxf(acc[mt][nt][r] + bj, 0.f));
      }
    }
  // stage out_w [128][128] fp32 -> bf16 B-layout owB[o][j]
#pragma unroll
  for (int i = 0; i < 16; ++i) {
    const int f = t + 256 * i;            // 0..4095 float4s
    const int o = f >> 5, j4 = (f & 31) * 4;
    const float4 v = *(const float4*)(outw + o * 128 + j4);
    uint2 pv;
    pv.x = (uint)f2b(v.x) | ((uint)f2b(v.y) << 16);
    pv.y = (uint)f2b(v.z) | ((uint)f2b(v.w) << 16);
    *(uint2*)&U.p2.owB[o][j4] = pv;
  }
  __syncthreads();

  // ---- phase2 MFMA: out = t @ out_w^T
  f32x4 acc2[2][8];
#pragma unroll
  for (int mt = 0; mt < 2; ++mt)
#pragma unroll
    for (int nt = 0; nt < 8; ++nt) acc2[mt][nt] = (f32x4){0.f, 0.f, 0.f, 0.f};

#pragma unroll
  for (int kk = 0; kk < 4; ++kk) {
    const int ko = kk * 32 + quad * 8;
    bf16x8 a[2], b[8];
#pragma unroll
    for (int mt = 0; mt < 2; ++mt)
      a[mt] = ldfrag(&U.p2.tA[32 * wv + 16 * mt + lm][ko]);
#pragma unroll
    for (int nt = 0; nt < 8; ++nt)
      b[nt] = ldfrag(&U.p2.owB[16 * nt + lm][ko]);
#pragma unroll
    for (int mt = 0; mt < 2; ++mt)
#pragma unroll
      for (int nt = 0; nt < 8; ++nt)
        acc2[mt][nt] = __builtin_amdgcn_mfma_f32_16x16x32_bf16(
            a[mt], b[nt], acc2[mt][nt], 0, 0, 0);
  }

  // epilogue: + out_b, fp32 stores (C layout: col=lm, row=quad*4+r)
#pragma unroll
  for (int mt = 0; mt < 2; ++mt)
#pragma unroll
    for (int nt = 0; nt < 8; ++nt) {
      const int col = 16 * nt + lm;
      const float bo = ob[col];
#pragma unroll
      for (int r = 0; r < 4; ++r) {
        const int srow = s0 + 32 * wv + 16 * mt + quad * 4 + r;
        out[(size_t)srow * 128 + col] = acc2[mt][nt][r] + bo;
      }
    }
}

extern "C" void kernel_launch(void* const* d_in, const int* in_sizes, int n_in,
                              void* d_out, int out_size, void* d_ws, size_t ws_size,
                              hipStream_t stream) {
  const float* x    = (const float*)d_in[0];
  const float* w1   = (const float*)d_in[1];
  const float* b1   = (const float*)d_in[2];
  const float* w2   = (const float*)d_in[3];
  const float* b2   = (const float*)d_in[4];
  const float* fc1w = (const float*)d_in[5];
  const float* fc1b = (const float*)d_in[6];
  const float* outw = (const float*)d_in[7];
  const float* outb = (const float*)d_in[8];
  float* outp = (float*)d_out;
  ushort* ws  = (ushort*)d_ws;   // h2 staging: N x 64 bf16 = 16.8 MB

  const int N = in_sizes[0] / 128;   // 131072

  conv_kernel<<<N / 256, 256, 0, stream>>>(x, w1, b1, w2, b2, ws);
  fc_kernel<<<N / 128, 256, 0, stream>>>(ws, fc1w, fc1b, outw, outb, outp);
}